// Round 3
// baseline (1112.363 us; speedup 1.0000x reference)
//
#include <hip/hip_runtime.h>

// ROUND 3: DIAGNOSTIC A/B. Four variants in one launch sequence, each with
// in-kernel work repetition so per-dispatch durations exceed the ~200us poison
// fills and show up in rocprof top-5 with their own counters.
//   S_nt    : pure 256MB nontemporal-store stream, 6 reps  (floor probe)
//   S_plain : same with plain stores, 6 reps               (nt effect probe)
//   A       : round-1 global-gather kernel, 4 reps
//   B       : round-2 LDS-bf16 kernel, 4 reps  (LAST -> validated output)
// `zero` (runtime 0) is mixed into per-rep indices so loads can't be hoisted.

typedef float f4 __attribute__((ext_vector_type(4)));
typedef unsigned short u16;
typedef u16 us4 __attribute__((ext_vector_type(4)));

constexpr int kN       = 512;
constexpr int kC4      = 16;
constexpr int kGroups  = 4;
constexpr int kStride  = 20;
constexpr int kParts   = 128;
constexpr int kThreads = 1024;

__device__ __forceinline__ u16 f32_to_bf16_rn(float f) {
    unsigned int u = __builtin_bit_cast(unsigned int, f);
    unsigned int r = (u + 0x7FFFu + ((u >> 16) & 1u)) >> 16;
    return (u16)r;
}
__device__ __forceinline__ float bf16_to_f32(u16 h) {
    unsigned int u = ((unsigned int)h) << 16;
    return __builtin_bit_cast(float, u);
}
__device__ __forceinline__ f4 us4_to_f4(us4 h) {
    f4 r;
    r.x = bf16_to_f32(h.x); r.y = bf16_to_f32(h.y);
    r.z = bf16_to_f32(h.z); r.w = bf16_to_f32(h.w);
    return r;
}

// ---------------- S: pure store probes ----------------
__global__ __launch_bounds__(256) void store_nt_kernel(f4* __restrict__ out,
                                                       int total, int zero, int reps) {
    int gid = blockIdx.x * 256 + threadIdx.x;
    if (gid >= total) return;
    f4 v = {0.f, 0.f, 0.f, 0.f};
    for (int r = 0; r < reps; ++r) {
        __builtin_nontemporal_store(v, &out[gid + zero * r]);
    }
}

__global__ __launch_bounds__(256) void store_plain_kernel(f4* __restrict__ out,
                                                          int total, int zero, int reps) {
    int gid = blockIdx.x * 256 + threadIdx.x;
    if (gid >= total) return;
    f4 v = {0.f, 0.f, 0.f, 0.f};
    for (int r = 0; r < reps; ++r) {
        out[gid + zero * r] = v;
    }
}

// ---------------- A: round-1 global-gather ----------------
__global__ __launch_bounds__(256) void triline_global_kernel(
    const float* __restrict__ coords,
    const f4* __restrict__ xl, const f4* __restrict__ yl, const f4* __restrict__ zl,
    const float* __restrict__ grid, f4* __restrict__ out,
    int total, int zero, int reps)
{
    int gid0 = blockIdx.x * 256 + threadIdx.x;
    if (gid0 >= total) return;
    for (int rep = 0; rep < reps; ++rep) {
        int gid = gid0 + zero * rep;          // opaque: forces full re-execution
        int b  = gid >> 4;
        int c4 = gid & 15;

        float g0     = grid[zero * rep];
        float inv_dg = 1.0f / (grid[1 + zero * rep] - g0);

        float cx = coords[3 * b + 0];
        float cy = coords[3 * b + 1];
        float cz = coords[3 * b + 2];

        float px = (cx - g0) * inv_dg;
        float py = (cy - g0) * inv_dg;
        float pz = (cz - g0) * inv_dg;

        int ix = min(max((int)floorf(px), 0), kN - 2);
        int iy = min(max((int)floorf(py), 0), kN - 2);
        int iz = min(max((int)floorf(pz), 0), kN - 2);

        float wx = px - (float)ix;
        float wy = py - (float)iy;
        float wz = pz - (float)iz;

        f4 x0 = xl[ix * kC4 + c4];
        f4 x1 = xl[ix * kC4 + kC4 + c4];
        f4 y0 = yl[iy * kC4 + c4];
        f4 y1 = yl[iy * kC4 + kC4 + c4];
        f4 z0 = zl[iz * kC4 + c4];
        f4 z1 = zl[iz * kC4 + kC4 + c4];

        f4 r = x0 + (x1 - x0) * wx;
        r    = r + y0 + (y1 - y0) * wy;
        r    = r + z0 + (z1 - z0) * wz;

        __builtin_nontemporal_store(r, &out[gid]);
    }
}

// ---------------- B: round-2 LDS bf16 ----------------
__global__ __launch_bounds__(kThreads) void triline_lds_kernel(
    const float* __restrict__ coords,
    const f4* __restrict__ xl, const f4* __restrict__ yl, const f4* __restrict__ zl,
    const float* __restrict__ grid, f4* __restrict__ out,
    int B, int zero, int reps)
{
    __shared__ u16 s_tab[3 * kN * kStride];   // 60 KiB

    const int tid   = threadIdx.x;
    const int g     = blockIdx.x & (kGroups - 1);
    const int part  = blockIdx.x >> 2;
    const int pts   = B / kParts;
    const int pbase = part * pts;

    for (int s = tid; s < 3 * kN * 4; s += kThreads) {
        int t  = s >> 11;
        int rq = s & 2047;
        int r  = rq >> 2;
        int q  = rq & 3;
        const f4* tp = (t == 0) ? xl : ((t == 1) ? yl : zl);
        f4 v = tp[r * kC4 + g * 4 + q];
        us4 h;
        h.x = f32_to_bf16_rn(v.x); h.y = f32_to_bf16_rn(v.y);
        h.z = f32_to_bf16_rn(v.z); h.w = f32_to_bf16_rn(v.w);
        *(us4*)&s_tab[t * (kN * kStride) + r * kStride + q * 4] = h;
    }

    float g0     = grid[0];
    float inv_dg = 1.0f / (grid[1] - g0);

    __syncthreads();

    const u16* sx = &s_tab[0];
    const u16* sy = &s_tab[kN * kStride];
    const u16* sz = &s_tab[2 * kN * kStride];

    const int items = pts * 4;
    for (int rep = 0; rep < reps; ++rep) {
        for (int i0 = tid; i0 < items; i0 += kThreads) {
            int i = i0 + zero * rep;          // opaque: forces re-execution
            int p = pbase + (i >> 2);
            int c = i & 3;
            if (p >= B) break;

            float cx = coords[3 * p + 0];
            float cy = coords[3 * p + 1];
            float cz = coords[3 * p + 2];

            float px = (cx - g0) * inv_dg;
            float py = (cy - g0) * inv_dg;
            float pz = (cz - g0) * inv_dg;

            int ix = min(max((int)floorf(px), 0), kN - 2);
            int iy = min(max((int)floorf(py), 0), kN - 2);
            int iz = min(max((int)floorf(pz), 0), kN - 2);

            float wx = px - (float)ix;
            float wy = py - (float)iy;
            float wz = pz - (float)iz;

            const u16* ax = sx + ix * kStride + c * 4;
            const u16* ay = sy + iy * kStride + c * 4;
            const u16* az = sz + iz * kStride + c * 4;

            f4 x0 = us4_to_f4(*(const us4*)ax);
            f4 x1 = us4_to_f4(*(const us4*)(ax + kStride));
            f4 y0 = us4_to_f4(*(const us4*)ay);
            f4 y1 = us4_to_f4(*(const us4*)(ay + kStride));
            f4 z0 = us4_to_f4(*(const us4*)az);
            f4 z1 = us4_to_f4(*(const us4*)(az + kStride));

            f4 r = x0 + (x1 - x0) * wx;
            r    = r + y0 + (y1 - y0) * wy;
            r    = r + z0 + (z1 - z0) * wz;

            out[p * kC4 + g * 4 + c] = r;
        }
    }
}

extern "C" void kernel_launch(void* const* d_in, const int* in_sizes, int n_in,
                              void* d_out, int out_size, void* d_ws, size_t ws_size,
                              hipStream_t stream) {
    const float* coords = (const float*)d_in[0];
    const f4*    xl     = (const f4*)d_in[1];
    const f4*    yl     = (const f4*)d_in[2];
    const f4*    zl     = (const f4*)d_in[3];
    const float* grid   = (const float*)d_in[4];
    f4*          out    = (f4*)d_out;

    int B     = in_sizes[0] / 3;            // 1048576
    int total = B * kC4;                    // 16M f4 chunks
    int zero  = (in_sizes[0] == 0) ? 1 : 0; // runtime 0, opaque to compiler

    int blocksS = (total + 255) / 256;

    // 1) pure-store probes (wrong data, overwritten below)
    store_nt_kernel   <<<blocksS, 256, 0, stream>>>(out, total, zero, 6);
    store_plain_kernel<<<blocksS, 256, 0, stream>>>(out, total, zero, 6);
    // 2) global-gather variant, 4 reps
    triline_global_kernel<<<blocksS, 256, 0, stream>>>(coords, xl, yl, zl, grid, out,
                                                       total, zero, 4);
    // 3) LDS variant, 4 reps — LAST, its output is what gets validated
    triline_lds_kernel<<<kGroups * kParts, kThreads, 0, stream>>>(coords, xl, yl, zl, grid, out,
                                                                  B, zero, 4);
}